// Round 7
// baseline (394.806 us; speedup 1.0000x reference)
//
#include <hip/hip_runtime.h>

// Problem constants (from reference)
#define B_      128
#define NPIX    32      // N = M = 32
#define NNEO    30      // N-2
#define NCH     19      // state channels (channel-planar layout)
#define PLANE   1024    // 32*32 floats per channel plane (global)
#define SROWS   10      // max staged rows per block (nr+2)
#define SPLANE  (SROWS * NPIX)   // 320 floats per LDS channel plane
#define OUTD    21      // OUT_DIM
#define ITERS   10
#define THRESHV 0.0007f
#define HSTRIDE 31      // s_h cell stride: gcd(31,32)=1 -> conflict-free

#define STATE_ELEMS (B_ * NCH * PLANE)             // 2,490,368 floats per buffer
#define NCELLS      (B_ * NNEO * NNEO)             // 115,200
#define CLASS_ELEMS (NCELLS * 3)                   // 345,600

// ---------------------------------------------------------------------------
// R17 = R0's QUARTER-SPLIT FULL-OCCUPANCY structure (1024 thr, 4 quarters,
// 2 blocks/CU = 32 waves/CU — the best measured latency-hiding) + R16's
// CHANNEL-PLANAR state (global + LDS — kills the 3.3M-cycle bank conflicts
// R0 paid on interleaved CPAD b128 reads).
// Measured matrix: half/16w + planar = 37us; quarter/32w + interleaved = 33us;
// this is the untested quarter/32w + planar cell. fv reads are immediate-
// offset ds_read_b32 (one base per patch point, offsets ch*1280B — fits the
// 16-bit DS offset), conflict-free (consecutive lanes -> consecutive addrs),
// ~13us/CU-step of LDS pipe at 4x duplication, overlappable with ~23us VALU
// at 8 waves/SIMD.
// Accumulation order per output unchanged from ALL passing versions.
// MODE: 0 = first step (state==0, perc=identity), 1 = mid, 2 = last.
// ---------------------------------------------------------------------------

__global__ void nca_init(float* __restrict__ stateA, float* __restrict__ stateB) {
    int idx = blockIdx.x * blockDim.x + threadIdx.x;
    const int total = B_ * 124 * NCH;
    if (idx >= total) return;
    int c  = idx % NCH;
    int t2 = idx / NCH;
    int cellp = t2 % 124;
    int b    = t2 / 124;
    int i, j;
    if (cellp < 32)      { i = 0;  j = cellp; }
    else if (cellp < 64) { i = 31; j = cellp - 32; }
    else { int k = cellp - 64; i = 1 + (k >> 1); j = (k & 1) ? 31 : 0; }
    size_t off = ((size_t)(b * NCH + c)) * PLANE + i * NPIX + j;
    stateA[off] = 0.0f;
    stateB[off] = 0.0f;
}

#define ROW8(A, x, wrp) do { const float xx_ = (x); \
    const float* __restrict__ w_ = (wrp); \
    _Pragma("unroll") for (int o_ = 0; o_ < 8; o_++) (A)[o_] += xx_ * w_[o_]; \
} while (0)

#define ROW6(A, x, wrp) do { const float xx_ = (x); \
    const float* __restrict__ w_ = (wrp); \
    _Pragma("unroll") for (int o_ = 0; o_ < 6; o_++) (A)[o_] += xx_ * w_[o_]; \
} while (0)

template<int MODE>
__global__ __launch_bounds__(1024, 8)
void nca_step(const float* __restrict__ img,
              const float* __restrict__ W1, const float* __restrict__ b1,
              const float* __restrict__ W2, const float* __restrict__ b2,
              const float* __restrict__ W3, const float* __restrict__ b3,
              const float* __restrict__ state_old, float* __restrict__ state_new,
              int* perc, float* __restrict__ guesses_out,
              float* __restrict__ class_out)
{
    __shared__ float s_state[NCH * SPLANE];       // 24.3 KB planar
    __shared__ float s_img[NPIX * NPIX];          // 4 KB
    __shared__ float s_h[256 * HSTRIDE];          // 31.7 KB  (total 60.2 KB)

    const int b   = blockIdx.y;
    const int rg  = blockIdx.x;                   // 4 groups: rows {8,8,7,7}
    const int i0  = (rg < 2) ? rg * 8 : 16 + (rg - 2) * 7;
    const int nr  = (rg < 2) ? 8 : 7;
    const int tid = threadIdx.x;
    const int qh  = __builtin_amdgcn_readfirstlane(tid >> 8);  // wave-uniform
    const int cell = tid & 255;
    const int qoff = (qh == 0) ? 0 : (qh == 1) ? 8 : (qh == 2) ? 14 : 22;
    const int off3 = 5 * qh;

    // ---- stage state rows [i0, i0+nr+2) planar, and the image -------------
    if (MODE != 0) {
        const float4* __restrict__ g4 = (const float4*)
            (state_old + (size_t)b * (NCH * PLANE) + i0 * NPIX);
        float4* s4 = (float4*)s_state;
        if (nr == 8) {        // 10 rows = 80 f4 per channel
            for (int t = tid; t < NCH * 80; t += 1024) {
                const int ch = t / 80, rem = t - ch * 80;
                s4[ch * 80 + rem] = g4[ch * 256 + rem];
            }
        } else {              // 9 rows = 72 f4 per channel
            for (int t = tid; t < NCH * 72; t += 1024) {
                const int ch = t / 72, rem = t - ch * 72;
                s4[ch * 80 + rem] = g4[ch * 256 + rem];
            }
        }
    }
    if (tid < 256)
        ((float4*)s_img)[tid] = ((const float4*)(img + (size_t)b * PLANE))[tid];
    __syncthreads();                              // B1

    const int cells = nr * NNEO;
    const bool active = cell < cells;

    int r = 0, j = 0, i = 0, gcell = 0, px = 0, py = 0;
    if (active) {
        r = cell / NNEO;
        j = cell - r * NNEO;
        i = i0 + r;
        gcell = (b * NNEO + i) * NNEO + j;
        if (MODE == 0) { px = i; py = j; }
        else           { px = perc[2 * gcell]; py = perc[2 * gcell + 1]; }
    }

    // ---------------- layer 1: 182 -> 30 (this thread: 8 @ qoff) -----------
    float h1[8];
#pragma unroll
    for (int q = 0; q < 8; q++) h1[q] = b1[qoff + q];
    if (active) {
        if (MODE == 0) {
#pragma clang loop unroll(disable)
            for (int pr = 0; pr < 3; pr++) {
#pragma clang loop unroll(disable)
                for (int pc = 0; pc < 3; pc++) {
                    const float iv = s_img[(px + pr) * NPIX + (py + pc)];
                    ROW8(h1, iv, W1 + (pr * 3 + pc) * 600 + qoff);
                }
            }
        } else {
#pragma clang loop unroll(disable)
            for (int pr = 0; pr < 3; pr++) {
#pragma clang loop unroll(disable)
                for (int pc = 0; pc < 3; pc++) {
                    const float iv = s_img[(px + pr) * NPIX + (py + pc)];
                    const float* __restrict__ wp =
                        W1 + (pr * 3 + pc) * 600 + qoff;
                    const int sb = (r + pr) * NPIX + (j + pc);
                    // 19 conflict-free ds_read_b32 off ONE base (imm offsets)
                    float fv[NCH];
#pragma unroll
                    for (int ch = 0; ch < NCH; ch++)
                        fv[ch] = s_state[ch * SPLANE + sb];
                    ROW8(h1, iv, wp);              // row 0: image
#pragma unroll
                    for (int ch = 0; ch < NCH; ch++)
                        ROW8(h1, fv[ch], wp + (ch + 1) * 30);
                }
            }
        }
        const float posx = (float)(px - 16) * 0.0625f;
        const float posy = (float)(py - 16) * 0.0625f;
        ROW8(h1, posx, W1 + 180 * 30 + qoff);
        ROW8(h1, posy, W1 + 181 * 30 + qoff);
#pragma unroll
        for (int q = 0; q < 8; q++) h1[q] = fmaxf(h1[q], 0.0f);
#pragma unroll
        for (int q = 0; q < 8; q++) s_h[cell * HSTRIDE + qoff + q] = h1[q];
    }
    __syncthreads();                              // B2: a1 visible

    // ---------------- layer 2: 30 -> 30 (this thread: 8 @ qoff) ------------
    float h2[8];
#pragma unroll
    for (int q = 0; q < 8; q++) h2[q] = b2[qoff + q];
    if (active) {
#pragma clang loop unroll(disable)
        for (int k = 0; k < 30; k++) {
            const float x = s_h[cell * HSTRIDE + k];
            ROW8(h2, x, W2 + k * 30 + qoff);
        }
#pragma unroll
        for (int q = 0; q < 8; q++) h2[q] = fmaxf(h2[q], 0.0f);
    }
    __syncthreads();                              // B3: all a1 reads done
    if (active) {
#pragma unroll
        for (int q = 0; q < 8; q++) s_h[cell * HSTRIDE + qoff + q] = h2[q];
    }
    __syncthreads();                              // B4: h2 visible

    // ---------------- layer 3: 30 -> 21 (quarter q: cols 5q..5q+5) ---------
    float o[6];
#pragma unroll
    for (int c = 0; c < 6; c++) o[c] = b3[off3 + c];
    if (active) {
#pragma clang loop unroll(disable)
        for (int k = 0; k < 30; k++) {
            const float x = s_h[cell * HSTRIDE + k];
            ROW6(o, x, W3 + k * 21 + off3);
        }

        const int cen  = (i + 1) * NPIX + (j + 1);    // global in-plane off
        const int lcen = (r + 1) * NPIX + (j + 1);    // LDS in-plane off
        if (MODE == 2) {
            float* __restrict__ g = guesses_out + (size_t)gcell * OUTD;
            if (qh == 0) {
#pragma unroll
                for (int c = 0; c < 6; c++) g[c] = o[c];
            } else {
#pragma unroll
                for (int c = 1; c < 6; c++) g[off3 + c] = o[c];
            }
            if (qh == 3) {
                float* __restrict__ cs = class_out + (size_t)gcell * 3;
#pragma unroll
                for (int cc = 0; cc < 3; cc++)
                    cs[cc] = s_state[(16 + cc) * SPLANE + lcen] + o[1 + cc];
            }
        } else {
            float* __restrict__ snp =
                state_new + (size_t)b * (NCH * PLANE) + cen;
            if (qh == 0) {              // channels 0..5
#pragma unroll
                for (int c = 0; c < 6; c++) {
                    const float old =
                        (MODE == 0) ? 0.0f : s_state[c * SPLANE + lcen];
                    snp[c * PLANE] = old + o[c];
                }
            } else if (qh == 1) {       // channels 6..10
#pragma unroll
                for (int c = 1; c < 6; c++) {
                    const int ch = 5 + c;
                    const float old =
                        (MODE == 0) ? 0.0f : s_state[ch * SPLANE + lcen];
                    snp[ch * PLANE] = old + o[c];
                }
            } else if (qh == 2) {       // channels 11..15
#pragma unroll
                for (int c = 1; c < 6; c++) {
                    const int ch = 10 + c;
                    const float old =
                        (MODE == 0) ? 0.0f : s_state[ch * SPLANE + lcen];
                    snp[ch * PLANE] = old + o[c];
                }
            } else {                    // channels 16..18 + movement
#pragma unroll
                for (int c = 1; c < 4; c++) {
                    const int ch = 15 + c;
                    const float old =
                        (MODE == 0) ? 0.0f : s_state[ch * SPLANE + lcen];
                    snp[ch * PLANE] = old + o[c];
                }
                int dxm = (o[4] > THRESHV) ? 1 : ((o[4] < -THRESHV) ? -1 : 0);
                int dym = (o[5] > THRESHV) ? 1 : ((o[5] < -THRESHV) ? -1 : 0);
                px += dxm; py += dym;
                px = (px < 0) ? 0 : ((px > NNEO - 1) ? NNEO - 1 : px);
                py = (py < 0) ? 0 : ((py > NNEO - 1) ? NNEO - 1 : py);
                perc[2 * gcell + 0] = px;
                perc[2 * gcell + 1] = py;
            }
        }
    }
}

extern "C" void kernel_launch(void* const* d_in, const int* in_sizes, int n_in,
                              void* d_out, int out_size, void* d_ws, size_t ws_size,
                              hipStream_t stream) {
    const float* img = (const float*)d_in[0];
    const float* W1  = (const float*)d_in[1];
    const float* b1  = (const float*)d_in[2];
    const float* W2  = (const float*)d_in[3];
    const float* b2  = (const float*)d_in[4];
    const float* W3  = (const float*)d_in[5];
    const float* b3  = (const float*)d_in[6];

    float* out = (float*)d_out;
    float* class_out   = out;                 // 345,600 floats
    float* guesses_out = out + CLASS_ELEMS;   // 2,419,200 floats

    float* stateA = (float*)d_ws;
    float* stateB = stateA + STATE_ELEMS;
    int*   perc   = (int*)(stateB + STATE_ELEMS);

    {
        const int total = B_ * 124 * NCH;
        nca_init<<<(total + 255) / 256, 256, 0, stream>>>(stateA, stateB);
    }

    const dim3 grid(4, B_);                   // 512 blocks = 2/CU exactly
    // t = 0: state==0, perc = identity; writes stateB + perc
    nca_step<0><<<grid, 1024, 0, stream>>>(img, W1, b1, W2, b2, W3, b3,
                                           stateA, stateB, perc,
                                           guesses_out, class_out);
    // t = 1..8: ping-pong
    for (int t = 1; t < ITERS - 1; t++) {
        const float* so = (t & 1) ? stateB : stateA;
        float*       sn = (t & 1) ? stateA : stateB;
        nca_step<1><<<grid, 1024, 0, stream>>>(img, W1, b1, W2, b2, W3, b3,
                                               so, sn, perc,
                                               guesses_out, class_out);
    }
    // t = 9 (odd): reads stateB, emits guesses + class only
    nca_step<2><<<grid, 1024, 0, stream>>>(img, W1, b1, W2, b2, W3, b3,
                                           stateB, stateA, perc,
                                           guesses_out, class_out);
}